// Round 1
// baseline (345.125 us; speedup 1.0000x reference)
//
#include <hip/hip_runtime.h>

#define BB 32
#define LL 512
#define EMB 128
#define RS 11
#define RR 5

__global__ __launch_bounds__(256) void region_encoder_kernel(
    const int* __restrict__ seq,
    const float* __restrict__ W,
    const float* __restrict__ U,
    float* __restrict__ out)
{
    // 32 lanes per output row; each lane owns one float4 (128 floats / row).
    const int row  = blockIdx.x * 8 + (threadIdx.x >> 5);   // row in [0, B*L)
    const int lane = threadIdx.x & 31;
    if (row >= BB * LL) return;

    const int b = row >> 9;       // row / 512
    const int l = row & 511;      // row % 512

    const int s = seq[row];

    const float4* W4 = (const float4*)(W + (size_t)s * EMB);
    const float4  t  = W4[lane];

    float4 m = make_float4(-INFINITY, -INFINITY, -INFINITY, -INFINITY);

    #pragma unroll
    for (int j = 0; j < RS; ++j) {
        const int p = l + j - RR;
        const int w = (p >= 0 && p < LL) ? seq[(b << 9) + p] : 0;
        const float4* U4 = (const float4*)(U + (size_t)(w * RS + j) * EMB);
        const float4 u = U4[lane];
        m.x = fmaxf(m.x, u.x * t.x);
        m.y = fmaxf(m.y, u.y * t.y);
        m.z = fmaxf(m.z, u.z * t.z);
        m.w = fmaxf(m.w, u.w * t.w);
    }

    float4 r;
    if (s != 0) {
        r = m;
    } else {
        r = make_float4(0.f, 0.f, 0.f, 0.f);
    }
    ((float4*)(out + (size_t)row * EMB))[lane] = r;
}

extern "C" void kernel_launch(void* const* d_in, const int* in_sizes, int n_in,
                              void* d_out, int out_size, void* d_ws, size_t ws_size,
                              hipStream_t stream)
{
    const int*   seq = (const int*)  d_in[0];   // (B, L, 1) int32
    const float* W   = (const float*)d_in[1];   // (VOCAB, EMB) f32
    const float* U   = (const float*)d_in[2];   // (VOCAB*RS, EMB) f32
    float* out = (float*)d_out;                 // (B, L, 1, EMB) f32

    const int rows = BB * LL;                   // 16384
    const int blocks = rows / 8;                // 2048 blocks of 256 threads
    region_encoder_kernel<<<blocks, 256, 0, stream>>>(seq, W, U, out);
}

// Round 3
// 336.154 us; speedup vs baseline: 1.0267x; 1.0267x over previous
//
#include <hip/hip_runtime.h>

#define BB 32
#define LL 512
#define EMB 128
#define RS 11
#define RR 5

typedef float f4 __attribute__((ext_vector_type(4)));

__global__ __launch_bounds__(256) void region_encoder_kernel(
    const int* __restrict__ seq,
    const float* __restrict__ W,
    const float* __restrict__ U,
    float* __restrict__ out)
{
    // 32 lanes per output row; each lane owns one float4 (128 floats / row).
    const int row  = blockIdx.x * 8 + (threadIdx.x >> 5);   // row in [0, B*L)
    const int lane = threadIdx.x & 31;

    const int b = row >> 9;       // row / 512
    const int l = row & 511;      // row % 512

    const int s = seq[row];

    const f4* W4 = (const f4*)(W + (size_t)s * EMB);
    const f4  t  = W4[lane];

    f4 m = (f4){-INFINITY, -INFINITY, -INFINITY, -INFINITY};

    #pragma unroll
    for (int j = 0; j < RS; ++j) {
        const int p = l + j - RR;
        const int w = (p >= 0 && p < LL) ? seq[(b << 9) + p] : 0;
        // U rows are touched ~once each (unique (token-occurrence, j) pairs):
        // stream them nontemporally to keep L2/L3 clean.
        const f4* U4 = (const f4*)(U + (size_t)(w * RS + j) * EMB);
        const f4 u = __builtin_nontemporal_load(U4 + lane);
        m.x = fmaxf(m.x, u.x * t.x);
        m.y = fmaxf(m.y, u.y * t.y);
        m.z = fmaxf(m.z, u.z * t.z);
        m.w = fmaxf(m.w, u.w * t.w);
    }

    f4 r;
    if (s != 0) {
        r = m;
    } else {
        r = (f4){0.f, 0.f, 0.f, 0.f};
    }
    __builtin_nontemporal_store(r, (f4*)(out + (size_t)row * EMB) + lane);
}

extern "C" void kernel_launch(void* const* d_in, const int* in_sizes, int n_in,
                              void* d_out, int out_size, void* d_ws, size_t ws_size,
                              hipStream_t stream)
{
    const int*   seq = (const int*)  d_in[0];   // (B, L, 1) int32
    const float* W   = (const float*)d_in[1];   // (VOCAB, EMB) f32
    const float* U   = (const float*)d_in[2];   // (VOCAB*RS, EMB) f32
    float* out = (float*)d_out;                 // (B, L, 1, EMB) f32

    const int rows = BB * LL;                   // 16384
    const int blocks = rows / 8;                // 2048 blocks of 256 threads
    region_encoder_kernel<<<blocks, 256, 0, stream>>>(seq, W, U, out);
}